// Round 3
// baseline (995.323 us; speedup 1.0000x reference)
//
#include <hip/hip_runtime.h>
#include <hip/hip_bf16.h>

// Problem dims
#define PP 512
#define QQ 64
#define BB 16
#define EE 256
#define HH 256
#define OO 256

typedef _Float16 half2_t __attribute__((ext_vector_type(2)));

__device__ __forceinline__ void unpack8h(const uint4 r, float* v) {
    const _Float16* s = (const _Float16*)&r;
#pragma unroll
    for (int i = 0; i < 8; i++) v[i] = (float)s[i];
}
__device__ __forceinline__ float fast_tanh(float x) {
    x = fminf(fmaxf(x, -15.f), 15.f);
    float e = __expf(2.f * x);
    return (e - 1.f) * __frcp_rn(e + 1.f);
}
__device__ __forceinline__ float fast_sigmoid(float x) {
    x = fminf(fmaxf(x, -30.f), 30.f);
    return __frcp_rn(1.f + __expf(-x));
}
__device__ __forceinline__ float fdot2f(half2_t a, half2_t b, float c) {
#if defined(__has_builtin)
#if __has_builtin(__builtin_amdgcn_fdot2)
    return __builtin_amdgcn_fdot2(a, b, c, false);
#else
    return (float)a[0] * (float)b[0] + (float)a[1] * (float)b[1] + c;
#endif
#else
    return (float)a[0] * (float)b[0] + (float)a[1] * (float)b[1] + c;
#endif
}

// ---------------------------------------------------------------------------
// Generic tiled GEMM: C[m,n] = epilogue( sum_k A[m,k] * B[n,k] )
// Tile 128x128, K-chunk 16, 256 threads, 8x8 micro-tile, fp32 accumulate.
// Output fp16. B (weight) is fp32, row n = B[n, 0:K].
// AMODE: 0 = A fp32 (row stride K)
//        2 = A concat: k<256 -> Af32 (fp32, row stride 256), k>=256 -> Ah (f16, row stride 256)
//        3 = A f16 (row stride K)
// EPI:   0 = none
//        1 = + bias[n] (fp32)
//        2 = sigmoid(acc) * gateC[m*256+n] (f16)   [only used with N=256]
// ---------------------------------------------------------------------------
template <int AMODE, int EPI>
__global__ __launch_bounds__(256) void gemm_k(
    const float* __restrict__ Af32,
    const _Float16* __restrict__ Ah,
    const float* __restrict__ Bw,
    const float* __restrict__ bias,
    const _Float16* __restrict__ gateC,
    _Float16* __restrict__ Cout, int M, int N, int K)
{
    __shared__ float As[16][128];
    __shared__ float Bs[16][128];
    const int tid = threadIdx.x;
    const int bm = blockIdx.x, bn = blockIdx.y;
    const int ra = tid >> 1;          // 0..127 : row within tile for staging
    const int ka = (tid & 1) * 8;     // 0 or 8 : k-offset within chunk
    const int tm = (tid >> 4) * 8;    // micro-tile row base
    const int tn = (tid & 15) * 8;    // micro-tile col base

    float acc[8][8];
#pragma unroll
    for (int i = 0; i < 8; i++)
#pragma unroll
        for (int j = 0; j < 8; j++) acc[i][j] = 0.f;

    const long arow = (long)bm * 128 + ra;
    const long brow = (long)bn * 128 + ra;

    for (int k0 = 0; k0 < K; k0 += 16) {
        float av[8], bv[8];
        const int kk = k0 + ka;
        if (AMODE == 0) {
            const float* p = Af32 + arow * K + kk;
            float4 r0 = *(const float4*)(p);
            float4 r1 = *(const float4*)(p + 4);
            av[0] = r0.x; av[1] = r0.y; av[2] = r0.z; av[3] = r0.w;
            av[4] = r1.x; av[5] = r1.y; av[6] = r1.z; av[7] = r1.w;
        } else if (AMODE == 3) {
            uint4 r = *(const uint4*)(Ah + arow * K + kk);
            unpack8h(r, av);
        } else { // AMODE == 2
            if (kk < 256) {
                const float* p = Af32 + arow * 256 + kk;
                float4 r0 = *(const float4*)(p);
                float4 r1 = *(const float4*)(p + 4);
                av[0] = r0.x; av[1] = r0.y; av[2] = r0.z; av[3] = r0.w;
                av[4] = r1.x; av[5] = r1.y; av[6] = r1.z; av[7] = r1.w;
            } else {
                uint4 r = *(const uint4*)(Ah + arow * 256 + (kk - 256));
                unpack8h(r, av);
            }
        }
        {
            const float* p = Bw + brow * K + kk;
            float4 r0 = *(const float4*)(p);
            float4 r1 = *(const float4*)(p + 4);
            bv[0] = r0.x; bv[1] = r0.y; bv[2] = r0.z; bv[3] = r0.w;
            bv[4] = r1.x; bv[5] = r1.y; bv[6] = r1.z; bv[7] = r1.w;
        }
        __syncthreads();
#pragma unroll
        for (int i = 0; i < 8; i++) { As[ka + i][ra] = av[i]; Bs[ka + i][ra] = bv[i]; }
        __syncthreads();
#pragma unroll
        for (int k = 0; k < 16; k++) {
            float a[8], b[8];
            *(float4*)&a[0] = *(const float4*)&As[k][tm];
            *(float4*)&a[4] = *(const float4*)&As[k][tm + 4];
            *(float4*)&b[0] = *(const float4*)&Bs[k][tn];
            *(float4*)&b[4] = *(const float4*)&Bs[k][tn + 4];
#pragma unroll
            for (int i = 0; i < 8; i++)
#pragma unroll
                for (int j = 0; j < 8; j++)
                    acc[i][j] = fmaf(a[i], b[j], acc[i][j]);
        }
    }

#pragma unroll
    for (int i = 0; i < 8; i++) {
        const long m = (long)bm * 128 + tm + i;
#pragma unroll
        for (int j = 0; j < 8; j++) {
            const int n = bn * 128 + tn + j;
            float v = acc[i][j];
            if (EPI == 1) v += bias[n];
            if (EPI == 2) v = fast_sigmoid(v) * (float)gateC[m * 256 + n];
            Cout[m * (long)N + n] = (_Float16)v;
        }
    }
}

// ---------------------------------------------------------------------------
// Fused attention: per block = one (p,b) pair (m = p*16+b).
// scores[q] = sum_h v_h * tanh(Wq[q,b,h] + Wp[p,b,h]);  a = softmax_q(scores)
// c[p,b,e] = sum_q a[q] * question[q,b,e]
// 256 threads = 4 waves; wave w handles q in [16w, 16w+16); lane covers 4 h.
// ---------------------------------------------------------------------------
__global__ __launch_bounds__(256) void attn_k(
    const float* __restrict__ question,  // (Q,B,E) fp32
    const float* __restrict__ vvec,      // (H,) fp32
    const _Float16* __restrict__ Wp,     // (P*B, H) f16
    const _Float16* __restrict__ Wq,     // (Q*B, H) f16
    _Float16* __restrict__ Cc)           // (P*B, E) f16 out
{
    __shared__ float sc[QQ];
    __shared__ float aw[QQ];
    const int tid = threadIdx.x;
    const int blk = blockIdx.x;   // m = p*16 + b
    const int b = blk & 15;
    const int wave = tid >> 6, lane = tid & 63;

    float wp0[4], vv[4];
#pragma unroll
    for (int j = 0; j < 4; j++) {
        wp0[j] = (float)Wp[(long)blk * 256 + lane + 64 * j];
        vv[j] = vvec[lane + 64 * j];
    }
#pragma unroll 2
    for (int qi = 0; qi < 16; qi++) {
        const int q = wave * 16 + qi;
        const _Float16* wqp = Wq + (long)(q * 16 + b) * 256;
        float s = 0.f;
#pragma unroll
        for (int j = 0; j < 4; j++) {
            float x = (float)wqp[lane + 64 * j] + wp0[j];
            s += fast_tanh(x) * vv[j];
        }
#pragma unroll
        for (int off = 32; off; off >>= 1) s += __shfl_xor(s, off, 64);
        if (lane == 0) sc[q] = s;
    }
    __syncthreads();
    if (tid < 64) {
        float s = sc[tid];
        float mx = s;
#pragma unroll
        for (int off = 32; off; off >>= 1) mx = fmaxf(mx, __shfl_xor(mx, off, 64));
        float e = __expf(s - mx);
        float sum = e;
#pragma unroll
        for (int off = 32; off; off >>= 1) sum += __shfl_xor(sum, off, 64);
        aw[tid] = e * __frcp_rn(sum);
    }
    __syncthreads();
    float acc = 0.f;
#pragma unroll 4
    for (int q = 0; q < QQ; q++) {
        acc = fmaf(aw[q], question[(long)(q * 16 + b) * 256 + tid], acc);
    }
    Cc[(long)blk * 256 + tid] = (_Float16)acc;
}

// ---------------------------------------------------------------------------
// GRU scan. 16 blocks (one per batch element b), 768 threads (one per gate row).
// w_hh row held in VGPRs as 128 fp16 pairs (fp32->fp16, 2^-11 rel). h state fp32
// in gate-thread registers; broadcast each step through LDS as fp16 pairs.
// gh_j = dot(h, w_hh[j,:]) + b_hh[j]; gates computed by threads 0..255.
// ---------------------------------------------------------------------------
__global__ __launch_bounds__(768, 3) void gru_k(
    const float* __restrict__ whh,    // (768,256) fp32
    const float* __restrict__ bhh,    // (768,) fp32
    const _Float16* __restrict__ gi,  // (P*B, 768) f16 (b_ih folded in)
    float* __restrict__ out)          // (P,B,O) fp32
{
    __shared__ uint4 hq[32];      // 256 fp16 values of h (packed pairs)
    __shared__ float gh[768];
    const int tid = threadIdx.x;
    const int b = blockIdx.x;

    // Load this thread's w_hh row into registers as fp16 pairs.
    half2_t w[128];
    {
        const float* wr = whh + (long)tid * 256;
#pragma unroll
        for (int i = 0; i < 64; i++) {
            float4 r = *(const float4*)(wr + i * 4);
            half2_t h0, h1;
            h0[0] = (_Float16)r.x; h0[1] = (_Float16)r.y;
            h1[0] = (_Float16)r.z; h1[1] = (_Float16)r.w;
            w[2 * i] = h0;
            w[2 * i + 1] = h1;
        }
    }
    const float bh = bhh[tid];
    float h = 0.f;
    if (tid < 32) hq[tid] = make_uint4(0u, 0u, 0u, 0u);
    __syncthreads();

    for (int t = 0; t < PP; t++) {
        const _Float16* gip = gi + ((long)t * 16 + b) * 768;
        float g0 = 0.f, g1 = 0.f, g2 = 0.f;
        if (tid < 256) {   // prefetch gi early; latency hidden by the matvec
            g0 = (float)gip[tid];
            g1 = (float)gip[tid + 256];
            g2 = (float)gip[tid + 512];
        }
        float acc0 = 0.f, acc1 = 0.f;
#pragma unroll
        for (int i = 0; i < 32; i++) {
            uint4 hp = hq[i];
            acc0 = fdot2f(w[i * 4 + 0], __builtin_bit_cast(half2_t, hp.x), acc0);
            acc1 = fdot2f(w[i * 4 + 1], __builtin_bit_cast(half2_t, hp.y), acc1);
            acc0 = fdot2f(w[i * 4 + 2], __builtin_bit_cast(half2_t, hp.z), acc0);
            acc1 = fdot2f(w[i * 4 + 3], __builtin_bit_cast(half2_t, hp.w), acc1);
        }
        gh[tid] = acc0 + acc1 + bh;
        __syncthreads();
        if (tid < 256) {
            float r = fast_sigmoid(g0 + gh[tid]);
            float z = fast_sigmoid(g1 + gh[tid + 256]);
            float n = fast_tanh(fmaf(r, gh[tid + 512], g2));
            h = (1.f - z) * n + z * h;
            out[((long)t * 16 + b) * 256 + tid] = h;
            ((_Float16*)hq)[tid] = (_Float16)h;
        }
        __syncthreads();
    }
}

// ---------------------------------------------------------------------------
extern "C" void kernel_launch(void* const* d_in, const int* in_sizes, int n_in,
                              void* d_out, int out_size, void* d_ws, size_t ws_size,
                              hipStream_t stream)
{
    const float* passage  = (const float*)d_in[0];   // (512,16,256) fp32
    const float* question = (const float*)d_in[1];   // (64,16,256) fp32
    const float* Wuq      = (const float*)d_in[2];   // (256,256) fp32
    const float* Wup      = (const float*)d_in[3];   // (256,256) fp32
    const float* vvec     = (const float*)d_in[4];   // (1,256) fp32
    const float* Wg       = (const float*)d_in[5];   // (512,512) fp32
    const float* w_ih     = (const float*)d_in[6];   // (768,256) fp32
    const float* w_hh     = (const float*)d_in[7];   // (768,256) fp32
    const float* b_ih     = (const float*)d_in[8];   // (768,) fp32
    const float* b_hh     = (const float*)d_in[9];   // (768,) fp32

    // Workspace layout (all fp16) — total footprint exactly 16 MiB.
    //   [0,      12.0MiB) : gi (8192x768)  — written LAST; overlaps Wq/Wp/c,
    //                        which are all dead by the time gi is produced.
    //     inside that region, earlier phases use:
    //       [0,     0.5MiB) : Wq (1024x256)   dead after attn
    //       [0.5,   4.5MiB) : Wp (8192x256)   dead after attn
    //       [4.5,   8.5MiB) : c  (8192x256)   dead after gate GEMM
    //   [12MiB, 16MiB)     : cg (8192x256)    alive until gi GEMM done
    char* ws = (char*)d_ws;
    _Float16* gi_ws = (_Float16*)(ws);
    _Float16* Wq_ws = (_Float16*)(ws);
    _Float16* Wp_ws = (_Float16*)(ws + (512u << 10));
    _Float16* c_ws  = (_Float16*)(ws + (4608u << 10));
    _Float16* cg_ws = (_Float16*)(ws + (12288u << 10));

    // 1) Wq = question @ Wuq^T   (1024 x 256, K=256)
    gemm_k<0, 0><<<dim3(8, 2), 256, 0, stream>>>(question, nullptr, Wuq, nullptr, nullptr,
                                                 Wq_ws, 1024, 256, 256);
    // 2) Wp = passage @ Wup^T    (8192 x 256, K=256)
    gemm_k<0, 0><<<dim3(64, 2), 256, 0, stream>>>(passage, nullptr, Wup, nullptr, nullptr,
                                                  Wp_ws, 8192, 256, 256);
    // 3) attention -> c (8192 x 256)
    attn_k<<<8192, 256, 0, stream>>>(question, vvec, Wp_ws, Wq_ws, c_ws);
    // 4) cg = sigmoid([passage,c] @ Wg[256:512]^T) * c   (8192 x 256, K=512)
    gemm_k<2, 2><<<dim3(64, 2), 256, 0, stream>>>(passage, c_ws, Wg + 256 * 512, nullptr, c_ws,
                                                  cg_ws, 8192, 256, 512);
    // 5) gi = cg @ w_ih^T + b_ih   (8192 x 768, K=256)
    gemm_k<3, 1><<<dim3(64, 6), 256, 0, stream>>>(nullptr, cg_ws, w_ih, b_ih, nullptr,
                                                  gi_ws, 8192, 768, 256);
    // 6) GRU scan -> out (fp32)
    gru_k<<<16, 768, 0, stream>>>(w_hh, b_hh, gi_ws, (float*)d_out);
}

// Round 4
// 948.947 us; speedup vs baseline: 1.0489x; 1.0489x over previous
//
#include <hip/hip_runtime.h>
#include <hip/hip_bf16.h>

// Problem dims
#define PP 512
#define QQ 64
#define BB 16
#define EE 256
#define HH 256
#define OO 256

typedef _Float16 half2_t __attribute__((ext_vector_type(2)));

__device__ __forceinline__ void unpack8h(const uint4 r, float* v) {
    const _Float16* s = (const _Float16*)&r;
#pragma unroll
    for (int i = 0; i < 8; i++) v[i] = (float)s[i];
}
__device__ __forceinline__ float fast_tanh(float x) {
    x = fminf(fmaxf(x, -15.f), 15.f);
    float e = __expf(2.f * x);
    return (e - 1.f) * __frcp_rn(e + 1.f);
}
__device__ __forceinline__ float fast_sigmoid(float x) {
    x = fminf(fmaxf(x, -30.f), 30.f);
    return __frcp_rn(1.f + __expf(-x));
}
__device__ __forceinline__ float fdot2f(half2_t a, half2_t b, float c) {
#if defined(__has_builtin)
#if __has_builtin(__builtin_amdgcn_fdot2)
    return __builtin_amdgcn_fdot2(a, b, c, false);
#else
    return (float)a[0] * (float)b[0] + (float)a[1] * (float)b[1] + c;
#endif
#else
    return (float)a[0] * (float)b[0] + (float)a[1] * (float)b[1] + c;
#endif
}

// ---------------------------------------------------------------------------
// Generic tiled GEMM: C[m,n] = epilogue( sum_k A[m,k] * B[n,k] )
// Tile 128x128, K-chunk 16, 256 threads, 8x8 micro-tile, fp32 accumulate.
// Output fp16. B (weight) is fp32, row n = B[n, 0:K].
// AMODE: 0 = A fp32 (row stride K)
//        2 = A concat: k<256 -> Af32 (fp32, row stride 256), k>=256 -> Ah (f16, row stride 256)
//        3 = A f16 (row stride K)
// EPI:   0 = none
//        1 = + bias[n] (fp32)
//        2 = sigmoid(acc) * gateC[m*256+n] (f16)   [only used with N=256]
// ---------------------------------------------------------------------------
template <int AMODE, int EPI>
__global__ __launch_bounds__(256) void gemm_k(
    const float* __restrict__ Af32,
    const _Float16* __restrict__ Ah,
    const float* __restrict__ Bw,
    const float* __restrict__ bias,
    const _Float16* __restrict__ gateC,
    _Float16* __restrict__ Cout, int M, int N, int K)
{
    __shared__ float As[16][128];
    __shared__ float Bs[16][128];
    const int tid = threadIdx.x;
    const int bm = blockIdx.x, bn = blockIdx.y;
    const int ra = tid >> 1;          // 0..127 : row within tile for staging
    const int ka = (tid & 1) * 8;     // 0 or 8 : k-offset within chunk
    const int tm = (tid >> 4) * 8;    // micro-tile row base
    const int tn = (tid & 15) * 8;    // micro-tile col base

    float acc[8][8];
#pragma unroll
    for (int i = 0; i < 8; i++)
#pragma unroll
        for (int j = 0; j < 8; j++) acc[i][j] = 0.f;

    const long arow = (long)bm * 128 + ra;
    const long brow = (long)bn * 128 + ra;

    for (int k0 = 0; k0 < K; k0 += 16) {
        float av[8], bv[8];
        const int kk = k0 + ka;
        if (AMODE == 0) {
            const float* p = Af32 + arow * K + kk;
            float4 r0 = *(const float4*)(p);
            float4 r1 = *(const float4*)(p + 4);
            av[0] = r0.x; av[1] = r0.y; av[2] = r0.z; av[3] = r0.w;
            av[4] = r1.x; av[5] = r1.y; av[6] = r1.z; av[7] = r1.w;
        } else if (AMODE == 3) {
            uint4 r = *(const uint4*)(Ah + arow * K + kk);
            unpack8h(r, av);
        } else { // AMODE == 2
            if (kk < 256) {
                const float* p = Af32 + arow * 256 + kk;
                float4 r0 = *(const float4*)(p);
                float4 r1 = *(const float4*)(p + 4);
                av[0] = r0.x; av[1] = r0.y; av[2] = r0.z; av[3] = r0.w;
                av[4] = r1.x; av[5] = r1.y; av[6] = r1.z; av[7] = r1.w;
            } else {
                uint4 r = *(const uint4*)(Ah + arow * 256 + (kk - 256));
                unpack8h(r, av);
            }
        }
        {
            const float* p = Bw + brow * K + kk;
            float4 r0 = *(const float4*)(p);
            float4 r1 = *(const float4*)(p + 4);
            bv[0] = r0.x; bv[1] = r0.y; bv[2] = r0.z; bv[3] = r0.w;
            bv[4] = r1.x; bv[5] = r1.y; bv[6] = r1.z; bv[7] = r1.w;
        }
        __syncthreads();
#pragma unroll
        for (int i = 0; i < 8; i++) { As[ka + i][ra] = av[i]; Bs[ka + i][ra] = bv[i]; }
        __syncthreads();
#pragma unroll
        for (int k = 0; k < 16; k++) {
            float a[8], b[8];
            *(float4*)&a[0] = *(const float4*)&As[k][tm];
            *(float4*)&a[4] = *(const float4*)&As[k][tm + 4];
            *(float4*)&b[0] = *(const float4*)&Bs[k][tn];
            *(float4*)&b[4] = *(const float4*)&Bs[k][tn + 4];
#pragma unroll
            for (int i = 0; i < 8; i++)
#pragma unroll
                for (int j = 0; j < 8; j++)
                    acc[i][j] = fmaf(a[i], b[j], acc[i][j]);
        }
    }

#pragma unroll
    for (int i = 0; i < 8; i++) {
        const long m = (long)bm * 128 + tm + i;
#pragma unroll
        for (int j = 0; j < 8; j++) {
            const int n = bn * 128 + tn + j;
            float v = acc[i][j];
            if (EPI == 1) v += bias[n];
            if (EPI == 2) v = fast_sigmoid(v) * (float)gateC[m * 256 + n];
            Cout[m * (long)N + n] = (_Float16)v;
        }
    }
}

// ---------------------------------------------------------------------------
// Fused attention: per block = one (p,b) pair (m = p*16+b).
// ---------------------------------------------------------------------------
__global__ __launch_bounds__(256) void attn_k(
    const float* __restrict__ question,  // (Q,B,E) fp32
    const float* __restrict__ vvec,      // (H,) fp32
    const _Float16* __restrict__ Wp,     // (P*B, H) f16
    const _Float16* __restrict__ Wq,     // (Q*B, H) f16
    _Float16* __restrict__ Cc)           // (P*B, E) f16 out
{
    __shared__ float sc[QQ];
    __shared__ float aw[QQ];
    const int tid = threadIdx.x;
    const int blk = blockIdx.x;   // m = p*16 + b
    const int b = blk & 15;
    const int wave = tid >> 6, lane = tid & 63;

    float wp0[4], vv[4];
#pragma unroll
    for (int j = 0; j < 4; j++) {
        wp0[j] = (float)Wp[(long)blk * 256 + lane + 64 * j];
        vv[j] = vvec[lane + 64 * j];
    }
#pragma unroll 2
    for (int qi = 0; qi < 16; qi++) {
        const int q = wave * 16 + qi;
        const _Float16* wqp = Wq + (long)(q * 16 + b) * 256;
        float s = 0.f;
#pragma unroll
        for (int j = 0; j < 4; j++) {
            float x = (float)wqp[lane + 64 * j] + wp0[j];
            s += fast_tanh(x) * vv[j];
        }
#pragma unroll
        for (int off = 32; off; off >>= 1) s += __shfl_xor(s, off, 64);
        if (lane == 0) sc[q] = s;
    }
    __syncthreads();
    if (tid < 64) {
        float s = sc[tid];
        float mx = s;
#pragma unroll
        for (int off = 32; off; off >>= 1) mx = fmaxf(mx, __shfl_xor(mx, off, 64));
        float e = __expf(s - mx);
        float sum = e;
#pragma unroll
        for (int off = 32; off; off >>= 1) sum += __shfl_xor(sum, off, 64);
        aw[tid] = e * __frcp_rn(sum);
    }
    __syncthreads();
    float acc = 0.f;
#pragma unroll 4
    for (int q = 0; q < QQ; q++) {
        acc = fmaf(aw[q], question[(long)(q * 16 + b) * 256 + tid], acc);
    }
    Cc[(long)blk * 256 + tid] = (_Float16)acc;
}

// ---------------------------------------------------------------------------
// GRU scan, v2. 16 blocks (one per batch b), 512 threads.
// Decomposition: thread (half, e), half = tid>>8, e = tid&255.
// Thread computes, for h-element e, the half-dot over k in [128*half, 128*half+128)
// of all three gate rows {e, e+256, e+512} of w_hh (held in VGPRs as fp16 pairs,
// 192 VGPRs). Upper half writes its 3 partials to LDS; lower half combines,
// applies gates, owns h[e] (fp32 in register), writes fp16 h to the
// double-buffered broadcast buffer. One partial-exchange barrier + one
// state-publish barrier per step; h broadcast reads are 16 ds_read_b128 per
// thread (128 per CU per step, vs 384 in v1).
// ---------------------------------------------------------------------------
__global__ __launch_bounds__(512, 2) void gru_k(
    const float* __restrict__ whh,    // (768,256) fp32
    const float* __restrict__ bhh,    // (768,) fp32
    const _Float16* __restrict__ gi,  // (P*B, 768) f16 (b_ih folded in)
    float* __restrict__ out)          // (P,B,O) fp32
{
    __shared__ __align__(16) _Float16 hbuf[2][256];
    __shared__ float part[3][256];
    const int tid = threadIdx.x;
    const int half = tid >> 8;
    const int e = tid & 255;
    const int b = blockIdx.x;
    const int koff = half * 128;

    // Load weight slices: rows e (r-gate), e+256 (z), e+512 (n), cols [koff, koff+128)
    half2_t wr[64], wz[64], wn[64];
    {
        const float* pr = whh + (long)e * 256 + koff;
        const float* pz = whh + (long)(e + 256) * 256 + koff;
        const float* pn = whh + (long)(e + 512) * 256 + koff;
#pragma unroll
        for (int j = 0; j < 32; j++) {
            float4 a = *(const float4*)(pr + 4 * j);
            float4 c = *(const float4*)(pz + 4 * j);
            float4 d = *(const float4*)(pn + 4 * j);
            half2_t t;
            t[0] = (_Float16)a.x; t[1] = (_Float16)a.y; wr[2 * j] = t;
            t[0] = (_Float16)a.z; t[1] = (_Float16)a.w; wr[2 * j + 1] = t;
            t[0] = (_Float16)c.x; t[1] = (_Float16)c.y; wz[2 * j] = t;
            t[0] = (_Float16)c.z; t[1] = (_Float16)c.w; wz[2 * j + 1] = t;
            t[0] = (_Float16)d.x; t[1] = (_Float16)d.y; wn[2 * j] = t;
            t[0] = (_Float16)d.z; t[1] = (_Float16)d.w; wn[2 * j + 1] = t;
        }
    }
    float b_r = 0.f, b_z = 0.f, b_n = 0.f;
    if (half == 0) {
        b_r = bhh[e];
        b_z = bhh[e + 256];
        b_n = bhh[e + 512];
        hbuf[0][e] = (_Float16)0.f;
    }
    float h = 0.f;
    __syncthreads();

    int cur = 0;
    for (int t = 0; t < PP; t++) {
        const _Float16* gip = gi + ((long)t * 16 + b) * 768;
        float g0 = 0.f, g1 = 0.f, g2 = 0.f;
        if (half == 0) {   // prefetch gi; latency hidden by the matvec
            g0 = (float)gip[e];
            g1 = (float)gip[e + 256];
            g2 = (float)gip[e + 512];
        }
        // Half-dot over this thread's 128-wide k-slice of the broadcast h.
        const uint4* hp4 = ((const uint4*)hbuf[cur]) + half * 16;
        float ar = 0.f, az = 0.f, an = 0.f;
#pragma unroll
        for (int j = 0; j < 16; j++) {
            uint4 hp = hp4[j];
            half2_t h0 = __builtin_bit_cast(half2_t, hp.x);
            half2_t h1 = __builtin_bit_cast(half2_t, hp.y);
            half2_t h2 = __builtin_bit_cast(half2_t, hp.z);
            half2_t h3 = __builtin_bit_cast(half2_t, hp.w);
            ar = fdot2f(wr[4 * j + 0], h0, ar);
            ar = fdot2f(wr[4 * j + 1], h1, ar);
            ar = fdot2f(wr[4 * j + 2], h2, ar);
            ar = fdot2f(wr[4 * j + 3], h3, ar);
            az = fdot2f(wz[4 * j + 0], h0, az);
            az = fdot2f(wz[4 * j + 1], h1, az);
            az = fdot2f(wz[4 * j + 2], h2, az);
            az = fdot2f(wz[4 * j + 3], h3, az);
            an = fdot2f(wn[4 * j + 0], h0, an);
            an = fdot2f(wn[4 * j + 1], h1, an);
            an = fdot2f(wn[4 * j + 2], h2, an);
            an = fdot2f(wn[4 * j + 3], h3, an);
        }
        if (half == 1) {
            part[0][e] = ar;
            part[1][e] = az;
            part[2][e] = an;
        }
        __syncthreads();
        if (half == 0) {
            float ghr = ar + part[0][e] + b_r;
            float ghz = az + part[1][e] + b_z;
            float ghn = an + part[2][e] + b_n;
            float r = fast_sigmoid(g0 + ghr);
            float z = fast_sigmoid(g1 + ghz);
            float n = fast_tanh(fmaf(r, ghn, g2));
            h = (1.f - z) * n + z * h;
            out[((long)t * 16 + b) * 256 + e] = h;
            hbuf[cur ^ 1][e] = (_Float16)h;
        }
        __syncthreads();
        cur ^= 1;
    }
}

// ---------------------------------------------------------------------------
extern "C" void kernel_launch(void* const* d_in, const int* in_sizes, int n_in,
                              void* d_out, int out_size, void* d_ws, size_t ws_size,
                              hipStream_t stream)
{
    const float* passage  = (const float*)d_in[0];   // (512,16,256) fp32
    const float* question = (const float*)d_in[1];   // (64,16,256) fp32
    const float* Wuq      = (const float*)d_in[2];   // (256,256) fp32
    const float* Wup      = (const float*)d_in[3];   // (256,256) fp32
    const float* vvec     = (const float*)d_in[4];   // (1,256) fp32
    const float* Wg       = (const float*)d_in[5];   // (512,512) fp32
    const float* w_ih     = (const float*)d_in[6];   // (768,256) fp32
    const float* w_hh     = (const float*)d_in[7];   // (768,256) fp32
    const float* b_ih     = (const float*)d_in[8];   // (768,) fp32
    const float* b_hh     = (const float*)d_in[9];   // (768,) fp32

    // Workspace layout (all fp16) — total footprint exactly 16 MiB.
    //   [0,      12.0MiB) : gi (8192x768)  — written LAST; overlaps Wq/Wp/c,
    //                        which are all dead by the time gi is produced.
    //       [0,     0.5MiB) : Wq (1024x256)   dead after attn
    //       [0.5,   4.5MiB) : Wp (8192x256)   dead after attn
    //       [4.5,   8.5MiB) : c  (8192x256)   dead after gate GEMM
    //   [12MiB, 16MiB)     : cg (8192x256)    alive until gi GEMM done
    char* ws = (char*)d_ws;
    _Float16* gi_ws = (_Float16*)(ws);
    _Float16* Wq_ws = (_Float16*)(ws);
    _Float16* Wp_ws = (_Float16*)(ws + (512u << 10));
    _Float16* c_ws  = (_Float16*)(ws + (4608u << 10));
    _Float16* cg_ws = (_Float16*)(ws + (12288u << 10));

    // 1) Wq = question @ Wuq^T   (1024 x 256, K=256)
    gemm_k<0, 0><<<dim3(8, 2), 256, 0, stream>>>(question, nullptr, Wuq, nullptr, nullptr,
                                                 Wq_ws, 1024, 256, 256);
    // 2) Wp = passage @ Wup^T    (8192 x 256, K=256)
    gemm_k<0, 0><<<dim3(64, 2), 256, 0, stream>>>(passage, nullptr, Wup, nullptr, nullptr,
                                                  Wp_ws, 8192, 256, 256);
    // 3) attention -> c (8192 x 256)
    attn_k<<<8192, 256, 0, stream>>>(question, vvec, Wp_ws, Wq_ws, c_ws);
    // 4) cg = sigmoid([passage,c] @ Wg[256:512]^T) * c   (8192 x 256, K=512)
    gemm_k<2, 2><<<dim3(64, 2), 256, 0, stream>>>(passage, c_ws, Wg + 256 * 512, nullptr, c_ws,
                                                  cg_ws, 8192, 256, 512);
    // 5) gi = cg @ w_ih^T + b_ih   (8192 x 768, K=256)
    gemm_k<3, 1><<<dim3(64, 6), 256, 0, stream>>>(nullptr, cg_ws, w_ih, b_ih, nullptr,
                                                  gi_ws, 8192, 768, 256);
    // 6) GRU scan -> out (fp32)
    gru_k<<<16, 512, 0, stream>>>(w_hh, b_hh, gi_ws, (float*)d_out);
}